// Round 10
// baseline (50.530 us; speedup 1.0000x reference)
//
#include <hip/hip_runtime.h>

typedef short bf16x8 __attribute__((ext_vector_type(8)));
typedef float f32x4  __attribute__((ext_vector_type(4)));

__device__ __forceinline__ unsigned short f2bf_rne(float x) {
  union { float f; unsigned u; } a; a.f = x;
  unsigned r = a.u + 0x7fffu + ((a.u >> 16) & 1u);   // round-to-nearest-even
  return (unsigned short)(r >> 16);
}

__device__ __forceinline__ float fast_exp2(float x) {
#if __has_builtin(__builtin_amdgcn_exp2f)
  return __builtin_amdgcn_exp2f(x);
#else
  float r; asm("v_exp_f32 %0, %1" : "=v"(r) : "v"(x)); return r;
#endif
}

__device__ __forceinline__ unsigned cvt_pk_bf16(float a, float b) {
  unsigned r; asm("v_cvt_pk_bf16_f32 %0, %1, %2" : "=v"(r) : "v"(a), "v"(b)); return r;
}

// vec:[N][3] f32, sph:[3][512] f32, wts:[512][64] f32, sigma:[1] f32 -> out:[N][64] f32
// 1024 thr/block (16 waves). Each wave owns rows {base..base+15} and {base+256..base+271}
// (two register-blocked row-tiles sharing all W-fragment LDS reads). 512 rows/block.
// Sphere positions (6 KB) are read straight from global — L1-resident, VMEM pipe —
// instead of LDS (which was the saturated pipe).
__global__ __launch_bounds__(1024, 4) void sph_enc_kernel(
    const float* __restrict__ vec,
    const float* __restrict__ sph,
    const float* __restrict__ wts,
    const float* __restrict__ sigp,
    float* __restrict__ out)
{
  // WT[c][k] bf16, c-major (1KB rows), XOR-swizzled byte^=(c&7)<<4.
  __shared__ __align__(16) unsigned char wlds[64 * 512 * 2];   // 64 KB

  const int tid  = threadIdx.x;
  const int lane = tid & 63;
  const int wave = tid >> 6;          // 0..15

  // ---- stage weights: [512][64] f32 -> bf16 WT[c][k] swizzled (r8 verbatim) ----
  {
    const int c    = tid & 63;
    const int kgrp = tid >> 6;                    // 0..15
    const int swz  = (c & 7) << 4;
    #pragma unroll
    for (int pass = 0; pass < 4; ++pass) {
      const int k0 = pass * 128 + (kgrp << 3);
      unsigned pk[4];
      #pragma unroll
      for (int i = 0; i < 4; ++i) {
        const unsigned lo = f2bf_rne(wts[(k0 + 2 * i)     * 64 + c]);
        const unsigned hi = f2bf_rne(wts[(k0 + 2 * i + 1) * 64 + c]);
        pk[i] = lo | (hi << 16);
      }
      *reinterpret_cast<uint4*>(wlds + (((c << 10) + (k0 << 1)) ^ swz)) =
          make_uint4(pk[0], pk[1], pk[2], pk[3]);
    }
  }
  __syncthreads();

  const float sigma = sigp[0];
  // arg = u*(u*C2 + C1) + K2 ; p = exp2(arg) ; u = 1 - cos
  const float C1 = -1.44269504f / (sigma * sigma);
  const float C2 = C1 * 0.16666667f;
  const float K2 = -__log2f(2.50662827463f * sigma);

  const int r16  = lane & 15;     // MFMA A-row / D-col index
  const int q    = lane >> 4;     // k-group
  const int row0 = (blockIdx.x << 9) + (wave << 4) + r16;   // tile-0 sample row
  const int row1 = row0 + 256;                              // tile-1 sample row

  const float nvx0 = -vec[row0 * 3 + 0];
  const float nvy0 = -vec[row0 * 3 + 1];
  const float nvz0 = -vec[row0 * 3 + 2];
  const float nvx1 = -vec[row1 * 3 + 0];
  const float nvy1 = -vec[row1 * 3 + 1];
  const float nvz1 = -vec[row1 * 3 + 2];

  f32x4 acc0[4], acc1[4];
  #pragma unroll
  for (int nb = 0; nb < 4; ++nb) {
    acc0[nb] = (f32x4){0.f, 0.f, 0.f, 0.f};
    acc1[nb] = (f32x4){0.f, 0.f, 0.f, 0.f};
  }
  float rsa0 = 0.f, rsb0 = 0.f, rsa1 = 0.f, rsb1 = 0.f;

  const int swz_r = (lane & 7) << 4;   // (c&7)==(lane&7) for every nb block

  #pragma unroll
  for (int kt = 0; kt < 16; ++kt) {
    const int j0 = kt * 32 + q * 8;    // this lane's 8 consecutive sphere indices
    union { bf16x8 v; unsigned u32[4]; } af0, af1;

    #pragma unroll
    for (int h = 0; h < 2; ++h) {      // 4 j's per half; reads shared by both tiles
      const int jh = j0 + 4 * h;
      const f32x4 X = *reinterpret_cast<const f32x4*>(&sph[jh]);
      const f32x4 Y = *reinterpret_cast<const f32x4*>(&sph[512 + jh]);
      const f32x4 Z = *reinterpret_cast<const f32x4*>(&sph[1024 + jh]);
      float p[4];
      #pragma unroll
      for (int e = 0; e < 4; ++e) {
        const float u = fmaf(nvx0, X[e], fmaf(nvy0, Y[e], fmaf(nvz0, Z[e], 1.0f)));
        p[e] = fast_exp2(fmaf(u, fmaf(u, C2, C1), K2));
      }
      rsa0 += p[0] + p[2];
      rsb0 += p[1] + p[3];
      af0.u32[2 * h]     = cvt_pk_bf16(p[0], p[1]);
      af0.u32[2 * h + 1] = cvt_pk_bf16(p[2], p[3]);
      #pragma unroll
      for (int e = 0; e < 4; ++e) {
        const float u = fmaf(nvx1, X[e], fmaf(nvy1, Y[e], fmaf(nvz1, Z[e], 1.0f)));
        p[e] = fast_exp2(fmaf(u, fmaf(u, C2, C1), K2));
      }
      rsa1 += p[0] + p[2];
      rsb1 += p[1] + p[3];
      af1.u32[2 * h]     = cvt_pk_bf16(p[0], p[1]);
      af1.u32[2 * h + 1] = cvt_pk_bf16(p[2], p[3]);
    }

    const int kbyte = j0 << 1;
    #pragma unroll
    for (int nb = 0; nb < 4; ++nb) {   // one W read feeds both row-tiles
      const bf16x8 bf = *reinterpret_cast<const bf16x8*>(
          wlds + (((((nb << 4) + r16) << 10) + kbyte) ^ swz_r));
      acc0[nb] = __builtin_amdgcn_mfma_f32_16x16x32_bf16(af0.v, bf, acc0[nb], 0, 0, 0);
      acc1[nb] = __builtin_amdgcn_mfma_f32_16x16x32_bf16(af1.v, bf, acc1[nb], 0, 0, 0);
    }
  }

  // row sums: lanes {l, l^16, l^32, l^48} share a row (per row-tile)
  float rsum0 = rsa0 + rsb0;
  float rsum1 = rsa1 + rsb1;
  rsum0 += __shfl_xor(rsum0, 16);
  rsum0 += __shfl_xor(rsum0, 32);
  rsum1 += __shfl_xor(rsum1, 16);
  rsum1 += __shfl_xor(rsum1, 32);

  // C/D layout: col = lane&15, row = (lane>>4)*4 + reg
  const int obase = (blockIdx.x << 9) + (wave << 4);
  #pragma unroll
  for (int reg = 0; reg < 4; ++reg) {
    const int orow = (q << 2) + reg;
    const float rinv0 = 1.0f / (__shfl(rsum0, orow) + 1e-8f);
    const float rinv1 = 1.0f / (__shfl(rsum1, orow) + 1e-8f);
    const int b0 = ((obase + orow) << 6) + r16;
    const int b1 = ((obase + 256 + orow) << 6) + r16;
    out[b0 +  0] = acc0[0][reg] * rinv0;
    out[b0 + 16] = acc0[1][reg] * rinv0;
    out[b0 + 32] = acc0[2][reg] * rinv0;
    out[b0 + 48] = acc0[3][reg] * rinv0;
    out[b1 +  0] = acc1[0][reg] * rinv1;
    out[b1 + 16] = acc1[1][reg] * rinv1;
    out[b1 + 32] = acc1[2][reg] * rinv1;
    out[b1 + 48] = acc1[3][reg] * rinv1;
  }
}

extern "C" void kernel_launch(void* const* d_in, const int* in_sizes, int n_in,
                              void* d_out, int out_size, void* d_ws, size_t ws_size,
                              hipStream_t stream) {
  const float* vec = (const float*)d_in[0];
  const float* sph = (const float*)d_in[1];
  const float* wts = (const float*)d_in[2];
  const float* sig = (const float*)d_in[3];
  float* out = (float*)d_out;
  const int n      = in_sizes[0] / 3;   // 262144
  const int blocks = n >> 9;            // 512 rows per block (16 waves x 2 tiles x 16)
  hipLaunchKernelGGL(sph_enc_kernel, dim3(blocks), dim3(1024), 0, stream,
                     vec, sph, wts, sig, out);
}

// Round 12
// 50.526 us; speedup vs baseline: 1.0001x; 1.0001x over previous
//
#include <hip/hip_runtime.h>

typedef short bf16x8 __attribute__((ext_vector_type(8)));
typedef float f32x4  __attribute__((ext_vector_type(4)));

__device__ __forceinline__ unsigned short f2bf_rne(float x) {
  union { float f; unsigned u; } a; a.f = x;
  unsigned r = a.u + 0x7fffu + ((a.u >> 16) & 1u);   // round-to-nearest-even
  return (unsigned short)(r >> 16);
}

__device__ __forceinline__ float fast_exp2(float x) {
#if __has_builtin(__builtin_amdgcn_exp2f)
  return __builtin_amdgcn_exp2f(x);
#else
  float r; asm("v_exp_f32 %0, %1" : "=v"(r) : "v"(x)); return r;
#endif
}

__device__ __forceinline__ unsigned cvt_pk_bf16(float a, float b) {
  unsigned r; asm("v_cvt_pk_bf16_f32 %0, %1, %2" : "=v"(r) : "v"(a), "v"(b)); return r;
}

// vec:[N][3] f32, sph:[3][512] f32, wts:[512][64] f32, sigma:[1] f32 -> out:[N][64] f32
// r8 structure verbatim; ONLY change: B-fragment LDS reads hoisted to the top of the
// kt body so they complete under the eval phase instead of stalling the MFMA cluster.
__global__ __launch_bounds__(1024, 4) void sph_enc_kernel(
    const float* __restrict__ vec,
    const float* __restrict__ sph,
    const float* __restrict__ wts,
    const float* __restrict__ sigp,
    float* __restrict__ out)
{
  // WT[c][k] bf16, c-major (1KB rows), XOR-swizzled byte^=(c&7)<<4.
  __shared__ __align__(16) unsigned char wlds[64 * 512 * 2];   // 64 KB
  __shared__ __align__(16) float slds[3 * 512];                // 6 KB

  const int tid  = threadIdx.x;
  const int lane = tid & 63;
  const int wave = tid >> 6;          // 0..15

  // ---- stage sphere_pos (1536 f32; stride loop covers all with 1024 thr) ----
  for (int i = tid; i < 1536; i += 1024) slds[i] = sph[i];

  // ---- stage weights: [512][64] f32 -> bf16 WT[c][k] swizzled (r8 verbatim) ----
  {
    const int c    = tid & 63;
    const int kgrp = tid >> 6;                    // 0..15
    const int swz  = (c & 7) << 4;
    #pragma unroll
    for (int pass = 0; pass < 4; ++pass) {
      const int k0 = pass * 128 + (kgrp << 3);
      unsigned pk[4];
      #pragma unroll
      for (int i = 0; i < 4; ++i) {
        const unsigned lo = f2bf_rne(wts[(k0 + 2 * i)     * 64 + c]);
        const unsigned hi = f2bf_rne(wts[(k0 + 2 * i + 1) * 64 + c]);
        pk[i] = lo | (hi << 16);
      }
      *reinterpret_cast<uint4*>(wlds + (((c << 10) + (k0 << 1)) ^ swz)) =
          make_uint4(pk[0], pk[1], pk[2], pk[3]);
    }
  }
  __syncthreads();

  const float sigma = sigp[0];
  // arg = u*(u*C2 + C1) + K2 ; p = exp2(arg) ; u = 1 - cos
  const float C1 = -1.44269504f / (sigma * sigma);
  const float C2 = C1 * 0.16666667f;
  const float K2 = -__log2f(2.50662827463f * sigma);

  const int r16  = lane & 15;     // MFMA A-row / D-col index
  const int q    = lane >> 4;     // k-group
  const int row0 = (blockIdx.x << 9) + (wave << 4) + r16;   // tile-0 sample row
  const int row1 = row0 + 256;                              // tile-1 sample row

  const float nvx0 = -vec[row0 * 3 + 0];
  const float nvy0 = -vec[row0 * 3 + 1];
  const float nvz0 = -vec[row0 * 3 + 2];
  const float nvx1 = -vec[row1 * 3 + 0];
  const float nvy1 = -vec[row1 * 3 + 1];
  const float nvz1 = -vec[row1 * 3 + 2];

  f32x4 acc0[4], acc1[4];
  #pragma unroll
  for (int nb = 0; nb < 4; ++nb) {
    acc0[nb] = (f32x4){0.f, 0.f, 0.f, 0.f};
    acc1[nb] = (f32x4){0.f, 0.f, 0.f, 0.f};
  }
  float rsa0 = 0.f, rsb0 = 0.f, rsa1 = 0.f, rsb1 = 0.f;

  const int swz_r = (lane & 7) << 4;   // (c&7)==(lane&7) for every nb block

  #pragma unroll
  for (int kt = 0; kt < 16; ++kt) {
    const int j0 = kt * 32 + q * 8;    // this lane's 8 consecutive sphere indices
    union { bf16x8 v; unsigned u32[4]; } af0, af1;

    // -- hoisted B-fragment reads: land during the eval phase below --
    const int kbyte = j0 << 1;
    bf16x8 bf0 = *reinterpret_cast<const bf16x8*>(
        wlds + (((((0 << 4) + r16) << 10) + kbyte) ^ swz_r));
    bf16x8 bf1 = *reinterpret_cast<const bf16x8*>(
        wlds + (((((1 << 4) + r16) << 10) + kbyte) ^ swz_r));
    bf16x8 bf2 = *reinterpret_cast<const bf16x8*>(
        wlds + (((((2 << 4) + r16) << 10) + kbyte) ^ swz_r));
    bf16x8 bf3 = *reinterpret_cast<const bf16x8*>(
        wlds + (((((3 << 4) + r16) << 10) + kbyte) ^ swz_r));

    #pragma unroll
    for (int h = 0; h < 2; ++h) {      // 4 j's per half; reads shared by both tiles
      const int jh = j0 + 4 * h;
      const f32x4 X = *reinterpret_cast<const f32x4*>(&slds[jh]);
      const f32x4 Y = *reinterpret_cast<const f32x4*>(&slds[512 + jh]);
      const f32x4 Z = *reinterpret_cast<const f32x4*>(&slds[1024 + jh]);
      float p[4];
      #pragma unroll
      for (int e = 0; e < 4; ++e) {
        const float u = fmaf(nvx0, X[e], fmaf(nvy0, Y[e], fmaf(nvz0, Z[e], 1.0f)));
        p[e] = fast_exp2(fmaf(u, fmaf(u, C2, C1), K2));
      }
      rsa0 += p[0] + p[2];
      rsb0 += p[1] + p[3];
      af0.u32[2 * h]     = cvt_pk_bf16(p[0], p[1]);
      af0.u32[2 * h + 1] = cvt_pk_bf16(p[2], p[3]);
      #pragma unroll
      for (int e = 0; e < 4; ++e) {
        const float u = fmaf(nvx1, X[e], fmaf(nvy1, Y[e], fmaf(nvz1, Z[e], 1.0f)));
        p[e] = fast_exp2(fmaf(u, fmaf(u, C2, C1), K2));
      }
      rsa1 += p[0] + p[2];
      rsb1 += p[1] + p[3];
      af1.u32[2 * h]     = cvt_pk_bf16(p[0], p[1]);
      af1.u32[2 * h + 1] = cvt_pk_bf16(p[2], p[3]);
    }

    acc0[0] = __builtin_amdgcn_mfma_f32_16x16x32_bf16(af0.v, bf0, acc0[0], 0, 0, 0);
    acc1[0] = __builtin_amdgcn_mfma_f32_16x16x32_bf16(af1.v, bf0, acc1[0], 0, 0, 0);
    acc0[1] = __builtin_amdgcn_mfma_f32_16x16x32_bf16(af0.v, bf1, acc0[1], 0, 0, 0);
    acc1[1] = __builtin_amdgcn_mfma_f32_16x16x32_bf16(af1.v, bf1, acc1[1], 0, 0, 0);
    acc0[2] = __builtin_amdgcn_mfma_f32_16x16x32_bf16(af0.v, bf2, acc0[2], 0, 0, 0);
    acc1[2] = __builtin_amdgcn_mfma_f32_16x16x32_bf16(af1.v, bf2, acc1[2], 0, 0, 0);
    acc0[3] = __builtin_amdgcn_mfma_f32_16x16x32_bf16(af0.v, bf3, acc0[3], 0, 0, 0);
    acc1[3] = __builtin_amdgcn_mfma_f32_16x16x32_bf16(af1.v, bf3, acc1[3], 0, 0, 0);
  }

  // row sums: lanes {l, l^16, l^32, l^48} share a row (per row-tile)
  float rsum0 = rsa0 + rsb0;
  float rsum1 = rsa1 + rsb1;
  rsum0 += __shfl_xor(rsum0, 16);
  rsum0 += __shfl_xor(rsum0, 32);
  rsum1 += __shfl_xor(rsum1, 16);
  rsum1 += __shfl_xor(rsum1, 32);

  // C/D layout: col = lane&15, row = (lane>>4)*4 + reg
  const int obase = (blockIdx.x << 9) + (wave << 4);
  #pragma unroll
  for (int reg = 0; reg < 4; ++reg) {
    const int orow = (q << 2) + reg;
    const float rinv0 = 1.0f / (__shfl(rsum0, orow) + 1e-8f);
    const float rinv1 = 1.0f / (__shfl(rsum1, orow) + 1e-8f);
    const int b0 = ((obase + orow) << 6) + r16;
    const int b1 = ((obase + 256 + orow) << 6) + r16;
    out[b0 +  0] = acc0[0][reg] * rinv0;
    out[b0 + 16] = acc0[1][reg] * rinv0;
    out[b0 + 32] = acc0[2][reg] * rinv0;
    out[b0 + 48] = acc0[3][reg] * rinv0;
    out[b1 +  0] = acc1[0][reg] * rinv1;
    out[b1 + 16] = acc1[1][reg] * rinv1;
    out[b1 + 32] = acc1[2][reg] * rinv1;
    out[b1 + 48] = acc1[3][reg] * rinv1;
  }
}

extern "C" void kernel_launch(void* const* d_in, const int* in_sizes, int n_in,
                              void* d_out, int out_size, void* d_ws, size_t ws_size,
                              hipStream_t stream) {
  const float* vec = (const float*)d_in[0];
  const float* sph = (const float*)d_in[1];
  const float* wts = (const float*)d_in[2];
  const float* sig = (const float*)d_in[3];
  float* out = (float*)d_out;
  const int n      = in_sizes[0] / 3;   // 262144
  const int blocks = n >> 9;            // 512 rows per block (16 waves x 2 tiles x 16)
  hipLaunchKernelGGL(sph_enc_kernel, dim3(blocks), dim3(1024), 0, stream,
                     vec, sph, wts, sig, out);
}